// Round 8
// baseline (43.411 us; speedup 1.0000x reference)
//
#include <hip/hip_runtime.h>

// input x: (B=256,T=600,J=25,C=3) f32; x[b,tt,n*5+p,c] = in[(b*600+tt)*75 + n*15 + p*3 + c]
// output: (B,5,1800,4,4) f32, windows concatenated along tout.
//
// R8: R7's structure (coalesced LDS stage -> slot-per-thread compute -> bank-padded
// obuf -> lane-contiguous cooperative store) with CH_=50: LDS 35.6 KB -> 4 blocks/CU
// (was 3), 3 barrier-pairs/block (was 6), 3072 blocks for better drain overlap.

#define T_ 600
#define CH_ 50
#define NCH_ 12   // 600/50
#define NSLOT_ (5 * 3 * CH_)   // 750 slots per block
#define NBATCH_ ((NSLOT_ + 255) / 256)

__global__ __launch_bounds__(256) void gauss_agg_kernel(const float* __restrict__ x,
                                                        float* __restrict__ out) {
    __shared__ float raw[(CH_ + 2) * 75];   // 15.6 KB staged input (chunk + halo)
    __shared__ float4 obuf[256 * 5];        // 20 KB; 80B/slot stride kills bank aliasing

    int blk = blockIdx.x;
    int ch  = blk % NCH_;
    int b   = blk / NCH_;

    int start = ch * CH_ - 1; if (start < 0) start = 0;
    int end   = ch * CH_ + CH_ + 1; if (end > T_) end = T_;
    int total = (end - start) * 75;

    // ---- phase 0: dense coalesced stage ----
    const float* src = x + ((size_t)b * T_ + start) * 75;
    for (int e = (int)threadIdx.x; e < total; e += 256) raw[e] = src[e];
    __syncthreads();

    int ofs = (ch == 0) ? 0 : 1;     // local row of tt = (tt - ch*CH_) + ofs
    const float w5[5] = {4.f, 2.f, 3.f, 2.f, 4.f};
    float4* outf4 = reinterpret_cast<float4*>(out);

    for (int m = 0; m < NBATCH_; ++m) {
        int s = m * 256 + (int)threadIdx.x;
        if (s < NSLOT_) {
            int n  = s / (3 * CH_);
            int q  = s - n * (3 * CH_);
            int w  = q / CH_;
            int tl = q - w * CH_;
            int tt = ch * CH_ + tl;
            int li = tl + ofs;

            bool boundary;
            if (w == 0)      boundary = (tt == 0) || (tt == 599);
            else if (w == 1) boundary = (tt == 0) || (tt == 299) || (tt == 300) || (tt == 599);
            else             boundary = (tt == 0) || (tt == 199) || (tt == 200) ||
                                        (tt == 399) || (tt == 400) || (tt == 599);

            const float* rc = &raw[li * 75 + n * 15];

            float s0=0.f,s1=0.f,s2=0.f, m0=0.f,m1=0.f,m2=0.f;
            float A00=0.f,A01=0.f,A02=0.f,A11=0.f,A12=0.f,A22=0.f;
            #pragma unroll
            for (int p = 0; p < 5; ++p) {
                float a = rc[p*3+0], c = rc[p*3+1], d = rc[p*3+2];
                s0 += a; s1 += c; s2 += d;
                m0 += w5[p]*a; m1 += w5[p]*c; m2 += w5[p]*d;
                A00 += a*a; A01 += a*c; A02 += a*d;
                A11 += c*c; A12 += c*d; A22 += d*d;
            }
            float mu0 = m0*(1.f/15.f), mu1 = m1*(1.f/15.f), mu2 = m2*(1.f/15.f);

            float inv = 0.2f;
            if (!boundary) {
                #pragma unroll
                for (int dstep = 0; dstep < 2; ++dstep) {
                    const float* rn = rc + (dstep ? 75 : -75);
                    #pragma unroll
                    for (int p = 0; p < 5; ++p) {
                        float a = rn[p*3+0], c = rn[p*3+1], d = rn[p*3+2];
                        s0 += a; s1 += c; s2 += d;
                        A00 += a*a; A01 += a*c; A02 += a*d;
                        A11 += c*c; A12 += c*d; A22 += d*d;
                    }
                }
                inv = 1.f/15.f;
            }

            float mb0 = s0*inv, mb1 = s1*inv, mb2 = s2*inv;
            float e00 = A00*inv - 2.f*mu0*mb0 + 2.f*mu0*mu0;
            float e01 = A01*inv - mu0*mb1 - mb0*mu1 + 2.f*mu0*mu1;
            float e02 = A02*inv - mu0*mb2 - mb0*mu2 + 2.f*mu0*mu2;
            float e11 = A11*inv - 2.f*mu1*mb1 + 2.f*mu1*mu1;
            float e12 = A12*inv - mu1*mb2 - mb1*mu2 + 2.f*mu1*mu2;
            float e22 = A22*inv - 2.f*mu2*mb2 + 2.f*mu2*mu2;

            int base = (int)threadIdx.x * 5;
            obuf[base + 0] = make_float4(e00, e01, e02, mu0);
            obuf[base + 1] = make_float4(e01, e11, e12, mu1);
            obuf[base + 2] = make_float4(e02, e12, e22, mu2);
            obuf[base + 3] = make_float4(mu0, mu1, mu2, 1.f);
        }
        __syncthreads();

        // ---- cooperative lane-contiguous store of this batch ----
        int nslots  = NSLOT_ - m * 256; if (nslots > 256) nslots = 256;
        int npieces = nslots * 4;
        #pragma unroll
        for (int k = 0; k < 4; ++k) {
            int f = k * 256 + (int)threadIdx.x;
            if (f < npieces) {
                int sl = f >> 2, pc = f & 3;
                int s2 = m * 256 + sl;
                int n  = s2 / (3 * CH_);
                int q  = s2 - n * (3 * CH_);
                int w  = q / CH_;
                int tl = q - w * CH_;
                int tt = ch * CH_ + tl;
                size_t o = ((size_t)(b * 5 + n) * 1800 + w * 600 + tt) * 4 + pc;
                outf4[o] = obuf[sl * 5 + pc];
            }
        }
        __syncthreads();
    }
}

extern "C" void kernel_launch(void* const* d_in, const int* in_sizes, int n_in,
                              void* d_out, int out_size, void* d_ws, size_t ws_size,
                              hipStream_t stream) {
    const float* x = (const float*)d_in[0];
    float* out = (float*)d_out;
    gauss_agg_kernel<<<256 * NCH_, 256, 0, stream>>>(x, out);
}